// Round 4
// baseline (217.586 us; speedup 1.0000x reference)
//
#include <hip/hip_runtime.h>
#include <hip/hip_bf16.h>
#include <math.h>

#define NB 8192
#define ND 1024
#define KEPS 1e-8f
#define SLOTS 128
#define NTILE 32          // 8192/256 tile grid
#define NWG 528           // NTILE*(NTILE+1)/2 (= 8*66, XCD-bijective)
#define NKT 16            // K-tiles of 64

typedef __attribute__((ext_vector_type(8))) __bf16 bf16x8;
typedef __attribute__((ext_vector_type(4))) float f32x4;

// ---------- helpers ----------
__device__ __forceinline__ unsigned int fmono(float f) {
    unsigned int b = __float_as_uint(f);
    return b ^ ((b & 0x80000000u) ? 0xFFFFFFFFu : 0x80000000u);
}
__device__ __forceinline__ unsigned short f2bf(float f) {
    union { float f; unsigned int u; } a;
    a.f = f;
    unsigned int lsb = (a.u >> 16) & 1u;
    a.u += 0x7fffu + lsb;
    return (unsigned short)(a.u >> 16);
}
__device__ __forceinline__ void gload_lds16(const void* g, void* l) {
    __builtin_amdgcn_global_load_lds(
        (const __attribute__((address_space(1))) unsigned int*)g,
        (__attribute__((address_space(3))) unsigned int*)l, 16, 0, 0);
}
__device__ __forceinline__ unsigned long long packmax(float mx, int mc) {
    return ((unsigned long long)fmono(mx) << 32) |
           (unsigned long long)(~(unsigned int)mc);
}

// ---------- kernel 1: row L2-normalize -> bf16 (wave per row) ----------
__global__ __launch_bounds__(256) void normalize_k(const float* __restrict__ x,
                                                   unsigned short* __restrict__ xnb) {
    int row = blockIdx.x * 4 + (threadIdx.x >> 6);
    int l = threadIdx.x & 63;
    const float4* xr = (const float4*)(x + (size_t)row * ND);
    float4 v[4];
    float ss = 0.f;
#pragma unroll
    for (int q = 0; q < 4; ++q) {
        v[q] = xr[q * 64 + l];
        ss += v[q].x * v[q].x + v[q].y * v[q].y + v[q].z * v[q].z + v[q].w * v[q].w;
    }
#pragma unroll
    for (int off = 1; off < 64; off <<= 1) ss += __shfl_xor(ss, off, 64);
    float scale = 1.0f / fmaxf(sqrtf(ss), KEPS);
    ushort4* o = (ushort4*)(xnb + (size_t)row * ND);
#pragma unroll
    for (int q = 0; q < 4; ++q) {
        ushort4 u;
        u.x = f2bf(v[q].x * scale);
        u.y = f2bf(v[q].y * scale);
        u.z = f2bf(v[q].z * scale);
        u.w = f2bf(v[q].w * scale);
        o[q * 64 + l] = u;
    }
}

// ---------- kernel 2: 256^2 8-phase (m201) bf16 MFMA cos-sim + fused argmax ----------
// LDS per buffer (64KB): A[mq][wM][64r][128B] @0, B[nq][wN][32c][128B] @32768.
// Read swizzle: byte-in-row ^= ((row&7)<<4)  (conflict-free b128);
// staging pre-applies the inverse on the global source (linear gload_lds dest).
// Stage order: A1(c+1)@p1, A0(c+2)@p2, B0(c+2)@p3, B1(c+2)@p4; vmcnt(6)/boundary.
#define FENCE_BARRIER() do { asm volatile("" ::: "memory"); \
    __builtin_amdgcn_s_barrier(); asm volatile("" ::: "memory"); } while (0)
#define LGKM0() do { asm volatile("s_waitcnt lgkmcnt(0)" ::: "memory"); \
    __builtin_amdgcn_sched_barrier(0); } while (0)
#define WAIT_VM6() asm volatile("s_waitcnt vmcnt(6)" ::: "memory")
#define WAIT_VM0() asm volatile("s_waitcnt vmcnt(0)" ::: "memory")

// H: 0=A0(@0) 1=A1(@16384) 2=B0(@32768) 3=B1(@49152); DB = buffer byte offset
#define STAGE(H, DB) do { \
    gload_lds16(sp[H][0], ldsb + (DB) + (H) * 16384 + wv * 1024); \
    gload_lds16(sp[H][1], ldsb + (DB) + (H) * 16384 + 8192 + wv * 1024); \
    sp[H][0] += 128; sp[H][1] += 128; } while (0)

#define LOAD_A(CB, MQ) do { \
    const char* Ab_ = ldsb + (CB) + ((MQ) * 2 + wM) * 8192 + rowOff; \
    _Pragma("unroll") for (int mi = 0; mi < 4; ++mi) { \
        af[mi][0] = *(const bf16x8*)(Ab_ + mi * 2048 + ks0); \
        af[mi][1] = *(const bf16x8*)(Ab_ + mi * 2048 + ks1); } } while (0)

#define LOAD_B(CB, BANK, NQ) do { \
    const char* Bb_ = ldsb + (CB) + 32768 + (NQ) * 16384 + wN * 4096 + rowOff; \
    _Pragma("unroll") for (int ni = 0; ni < 2; ++ni) { \
        BANK[ni][0] = *(const bf16x8*)(Bb_ + ni * 2048 + ks0); \
        BANK[ni][1] = *(const bf16x8*)(Bb_ + ni * 2048 + ks1); } } while (0)

#define MFMAQ(MH, NH, BANK) do { \
    __builtin_amdgcn_s_setprio(1); \
    _Pragma("unroll") for (int mi = 0; mi < 4; ++mi) \
    _Pragma("unroll") for (int ni = 0; ni < 2; ++ni) { \
        acc[(MH) * 4 + mi][(NH) * 2 + ni] = __builtin_amdgcn_mfma_f32_16x16x32_bf16( \
            af[mi][0], BANK[ni][0], acc[(MH) * 4 + mi][(NH) * 2 + ni], 0, 0, 0); \
        acc[(MH) * 4 + mi][(NH) * 2 + ni] = __builtin_amdgcn_mfma_f32_16x16x32_bf16( \
            af[mi][1], BANK[ni][1], acc[(MH) * 4 + mi][(NH) * 2 + ni], 0, 0, 0); } \
    __builtin_amdgcn_s_setprio(0); } while (0)

// one K-tile: compute from CB, p1 stages next-tile A1 into DB, p2-4 stage
// tile+2's A0/B0/B1 into CB (regions freed by p1/p1/p2 reads respectively).
#define KTILE(CB, DB, S1, S2, FINAL) do { \
    bf16x8 af[4][2], b0[2][2], b1[2][2]; \
    LOAD_A(CB, 0); LOAD_B(CB, b0, 0); \
    if (S1) STAGE(1, DB); \
    FENCE_BARRIER(); LGKM0(); MFMAQ(0, 0, b0); FENCE_BARRIER(); \
    LOAD_B(CB, b1, 1); \
    if (S2) STAGE(0, CB); \
    FENCE_BARRIER(); LGKM0(); MFMAQ(0, 1, b1); FENCE_BARRIER(); \
    LOAD_A(CB, 1); \
    if (S2) STAGE(2, CB); \
    FENCE_BARRIER(); LGKM0(); MFMAQ(1, 1, b1); FENCE_BARRIER(); \
    if (S2) STAGE(3, CB); \
    FENCE_BARRIER(); MFMAQ(1, 0, b0); \
    if (FINAL) { WAIT_VM0(); } else { WAIT_VM6(); } \
    FENCE_BARRIER(); } while (0)

#define KTILE_LAST(CB) do { \
    bf16x8 af[4][2], b0[2][2], b1[2][2]; \
    LOAD_A(CB, 0); LOAD_B(CB, b0, 0); \
    FENCE_BARRIER(); LGKM0(); MFMAQ(0, 0, b0); FENCE_BARRIER(); \
    LOAD_B(CB, b1, 1); \
    FENCE_BARRIER(); LGKM0(); MFMAQ(0, 1, b1); FENCE_BARRIER(); \
    LOAD_A(CB, 1); \
    FENCE_BARRIER(); LGKM0(); MFMAQ(1, 1, b1); FENCE_BARRIER(); \
    MFMAQ(1, 0, b0); } while (0)

__global__ __launch_bounds__(512, 2) void argmax_gemm(const unsigned short* __restrict__ xnb,
                                                      unsigned long long* __restrict__ partial) {
    extern __shared__ char ldsb[];

    // T1: XCD-bijective swizzle, then triangular decode
    int wg = (int)blockIdx.x;
    int tile = (wg & 7) * (NWG / 8) + (wg >> 3);
    int by = 0, tr = tile;
    while (tr >= NTILE - by) { tr -= NTILE - by; ++by; }
    const int bx = by + tr;  // bx >= by

    const int rowBase = by * 256, colBase = bx * 256;
    const int tid = (int)threadIdx.x;
    const int wv = tid >> 6;   // 0..7
    const int l = tid & 63;
    const int wM = wv >> 2;    // 2 wave-rows x 128
    const int wN = wv & 3;     // 4 wave-cols x 64

    // read-side lane constants (swizzle XOR is lane-constant: row&7 == l&7)
    const int rowOff = (l & 15) * 128;
    const int ks0 = (((l >> 4) * 16)) ^ ((l & 7) << 4);
    const int ks1 = (64 | ((l >> 4) * 16)) ^ ((l & 7) << 4);

    // stage-side: chunk (wv,q) covers region rows (q*8+wv)*8 + (l>>3), 16B col (l&7)
    // source col pre-swizzled: cb = ((l&7) ^ (l>>3)) << 4
    const int scol = (((l & 7) ^ (l >> 3)) << 4);
    const char* xb = (const char*)xnb;
    const char* sp[4][2];
#pragma unroll
    for (int q = 0; q < 2; ++q) {
        int R = (q * 8 + wv) * 8 + (l >> 3);            // 0..127
        int arow = (R >> 6) * 128 + (R & 63);           // + mq*64
        int bcol = (R >> 5) * 64 + (R & 31);            // + nq*32
        sp[0][q] = xb + (size_t)(rowBase + arow) * 2048 + scol;
        sp[1][q] = xb + (size_t)(rowBase + arow + 64) * 2048 + scol;
        sp[2][q] = xb + (size_t)(colBase + bcol) * 2048 + scol;
        sp[3][q] = xb + (size_t)(colBase + bcol + 32) * 2048 + scol;
    }

    f32x4 acc[8][4];
#pragma unroll
    for (int m = 0; m < 8; ++m)
#pragma unroll
        for (int n = 0; n < 4; ++n) acc[m][n] = f32x4{0.f, 0.f, 0.f, 0.f};

    // prologue: t0 fully + t1 {A0,B0,B1}; confirm t0, leave 3 half-tiles in flight
    STAGE(0, 0); STAGE(2, 0); STAGE(3, 0); STAGE(1, 0);
    STAGE(0, 65536); STAGE(2, 65536); STAGE(3, 65536);
    WAIT_VM6();
    FENCE_BARRIER();

    // main: tiles 0..13 (all stages active, vmcnt(6) boundaries)
    for (int c = 0; c < 12; c += 2) {
        KTILE(0, 65536, true, true, false);
        KTILE(65536, 0, true, true, false);
    }
    KTILE(0, 65536, true, true, false);        // tile 12
    KTILE(65536, 0, true, true, false);        // tile 13
    KTILE(0, 65536, true, false, true);        // tile 14: stage t15.A1 only; drain
    KTILE_LAST(65536);                         // tile 15

    // ---- epilogue: fused argmax. C/D: col = lane&15, row = (lane>>4)*4 + reg ----
#pragma unroll
    for (int m = 0; m < 8; ++m) {
#pragma unroll
        for (int r = 0; r < 4; ++r) {
            int gi = rowBase + wM * 128 + m * 16 + (l >> 4) * 4 + r;
            float mx = -3.0f;
            int mc = 0x7FFFFFFF;
#pragma unroll
            for (int n = 0; n < 4; ++n) {
                int gj = colBase + wN * 64 + n * 16 + (l & 15);
                float v = (gi == gj) ? -2.0f : acc[m][n][r];
                if (v > mx) { mx = v; mc = gj; }
            }
#pragma unroll
            for (int off = 1; off < 16; off <<= 1) {
                float omx = __shfl_xor(mx, off, 64);
                int omc = __shfl_xor(mc, off, 64);
                if (omx > mx || (omx == mx && omc < mc)) { mx = omx; mc = omc; }
            }
            if ((l & 15) == 0)
                partial[(size_t)gi * SLOTS + (2 * by + (bx - by) * 4 + wN)] = packmax(mx, mc);
        }
    }
    if (bx > by) {
#pragma unroll
        for (int n = 0; n < 4; ++n) {
            int gj = colBase + wN * 64 + n * 16 + (l & 15);
            float mx = -3.0f;
            int mc = 0x7FFFFFFF;
#pragma unroll
            for (int m = 0; m < 8; ++m) {
#pragma unroll
                for (int r = 0; r < 4; ++r) {
                    int gi = rowBase + wM * 128 + m * 16 + (l >> 4) * 4 + r;
                    float v = (gi == gj) ? -2.0f : acc[m][n][r];
                    if (v > mx) { mx = v; mc = gi; }
                }
            }
#pragma unroll
            for (int off = 16; off < 64; off <<= 1) {
                float omx = __shfl_xor(mx, off, 64);
                int omc = __shfl_xor(mc, off, 64);
                if (omx > mx || (omx == mx && omc < mc)) { mx = omx; mc = omc; }
            }
            if ((l >> 4) == 0)
                partial[(size_t)gj * SLOTS + (2 * by + wM)] = packmax(mx, mc);
        }
    }
}

// ---------- kernel 3: slot-reduce -> NN idx; exact fp32 distance + loss (wave/row) ----------
__global__ __launch_bounds__(256) void dist_k(const float* __restrict__ x,
                                              const unsigned long long* __restrict__ partial,
                                              float* __restrict__ rowloss) {
    int i = blockIdx.x * 4 + (threadIdx.x >> 6);
    int l = threadIdx.x & 63;
    int nv = SLOTS - 2 * (i >> 8);
    unsigned long long p = 0ull;
    if (l < nv) p = partial[(size_t)i * SLOTS + l];
    if (l + 64 < nv) {
        unsigned long long o = partial[(size_t)i * SLOTS + l + 64];
        if (o > p) p = o;
    }
#pragma unroll
    for (int off = 1; off < 64; off <<= 1) {
        unsigned long long o = __shfl_xor(p, off, 64);
        if (o > p) p = o;
    }
    int j = (int)(~(unsigned int)(p & 0xFFFFFFFFull));  // wave-uniform

    const float4* xi = (const float4*)(x + (size_t)i * ND);
    const float4* xj = (const float4*)(x + (size_t)j * ND);
    float4 a[4], b[4];
    float sa = 0.f, sb = 0.f;
#pragma unroll
    for (int q = 0; q < 4; ++q) {
        a[q] = xi[q * 64 + l];
        b[q] = xj[q * 64 + l];
        sa += a[q].x * a[q].x + a[q].y * a[q].y + a[q].z * a[q].z + a[q].w * a[q].w;
        sb += b[q].x * b[q].x + b[q].y * b[q].y + b[q].z * b[q].z + b[q].w * b[q].w;
    }
#pragma unroll
    for (int off = 1; off < 64; off <<= 1) {
        sa += __shfl_xor(sa, off, 64);
        sb += __shfl_xor(sb, off, 64);
    }
    float ia = 1.0f / fmaxf(sqrtf(sa), KEPS);
    float ib = 1.0f / fmaxf(sqrtf(sb), KEPS);
    float ss = 0.f;
#pragma unroll
    for (int q = 0; q < 4; ++q) {
        float dx = a[q].x * ia - b[q].x * ib + KEPS;
        float dy = a[q].y * ia - b[q].y * ib + KEPS;
        float dz = a[q].z * ia - b[q].z * ib + KEPS;
        float dw = a[q].w * ia - b[q].w * ib + KEPS;
        ss += dx * dx + dy * dy + dz * dz + dw * dw;
    }
#pragma unroll
    for (int off = 1; off < 64; off <<= 1) ss += __shfl_xor(ss, off, 64);
    if (l == 0) rowloss[i] = -logf(sqrtf(ss) + KEPS);
}

// ---------- kernel 4: mean over rows ----------
__global__ __launch_bounds__(1024) void reduce_k(const float* __restrict__ rowloss,
                                                 float* __restrict__ out) {
    int t = threadIdx.x;
    float s = 0.0f;
#pragma unroll
    for (int k = 0; k < 8; ++k) s += rowloss[t + k * 1024];
#pragma unroll
    for (int off = 32; off > 0; off >>= 1) s += __shfl_down(s, off, 64);
    __shared__ float sred[16];
    if ((t & 63) == 0) sred[t >> 6] = s;
    __syncthreads();
    if (t == 0) {
        float tot = 0.0f;
        for (int k = 0; k < 16; ++k) tot += sred[k];
        out[0] = tot / (float)NB;
    }
}

// ---------- launch ----------
extern "C" void kernel_launch(void* const* d_in, const int* in_sizes, int n_in,
                              void* d_out, int out_size, void* d_ws, size_t ws_size,
                              hipStream_t stream) {
    const float* x = (const float*)d_in[0];
    float* out = (float*)d_out;

    char* ws = (char*)d_ws;
    unsigned short* xnb = (unsigned short*)ws;                        // 16 MB
    unsigned long long* partial =
        (unsigned long long*)(ws + (size_t)NB * ND * 2);              // 8 MB
    float* rowloss = (float*)(ws + (size_t)NB * ND * 2 + (size_t)NB * SLOTS * 8);

    (void)hipFuncSetAttribute((const void*)argmax_gemm,
                              hipFuncAttributeMaxDynamicSharedMemorySize, 131072);

    normalize_k<<<NB / 4, 256, 0, stream>>>(x, xnb);
    argmax_gemm<<<NWG, 512, 131072, stream>>>(xnb, partial);
    dist_k<<<NB / 4, 256, 0, stream>>>(x, partial, rowloss);
    reduce_k<<<1, 1024, 0, stream>>>(rowloss, out);
}